// Round 9
// baseline (430.087 us; speedup 1.0000x reference)
//
#include <hip/hip_runtime.h>
#include <hip/hip_bf16.h>

typedef __bf16 bf16;
typedef __bf16 bf16x4 __attribute__((ext_vector_type(4)));
typedef __bf16 bf16x8 __attribute__((ext_vector_type(8)));
typedef float  f32x4  __attribute__((ext_vector_type(4)));

#define MFMA(a,b,c) __builtin_amdgcn_mfma_f32_16x16x32_bf16(a,b,c,0,0,0)

__device__ __forceinline__ void load_lds16(const void* gptr, void* lptr) {
  __builtin_amdgcn_global_load_lds(
      (const __attribute__((address_space(1))) void*)gptr,
      (__attribute__((address_space(3))) void*)lptr, 16, 0, 0);
}

// ---------------- conversion / transpose kernels ----------------

__global__ void cvt_bf16(const float* __restrict__ in, bf16* __restrict__ out, int n4) {
  int i = blockIdx.x * blockDim.x + threadIdx.x;
  if (i >= n4) return;
  float4 v = ((const float4*)in)[i];
  bf16x4 o = { (bf16)v.x, (bf16)v.y, (bf16)v.z, (bf16)v.w };
  ((bf16x4*)out)[i] = o;
}

// src: [2048][ncols] f32 ; dst: [ncols][2048] bf16 (row stride 2048)
__global__ void transpose_w(const float* __restrict__ src, bf16* __restrict__ dst, int ncols) {
  __shared__ float tl[32][33];
  int n0 = blockIdx.x * 32, k0 = blockIdx.y * 32;
  int tx = threadIdx.x, ty = threadIdx.y;
  for (int i = 0; i < 4; ++i)
    tl[ty + i*8][tx] = src[(size_t)(k0 + ty + i*8) * ncols + n0 + tx];
  __syncthreads();
  for (int i = 0; i < 4; ++i)
    dst[(size_t)(n0 + ty + i*8) * 2048 + k0 + tx] = (bf16)tl[tx][ty + i*8];
}

__global__ void concat_bias(const float* __restrict__ qb, const float* __restrict__ kb,
                            const float* __restrict__ vb, float* __restrict__ o) {
  int i = blockIdx.x * 256 + threadIdx.x;
  if (i >= 2304) return;
  o[i] = (i < 2048) ? qb[i] : (i < 2176 ? kb[i - 2048] : vb[i - 2176]);
}

// ---------------- GEMM: C[M,N] = A[M,K] @ Bt[N,K]^T + bias ----------------
// m97 structure + bijective XCD swizzle (grid total must be %8==0).

template<bool OUT_F32>
__global__ __launch_bounds__(256) void gemm_bt(
    const bf16* __restrict__ A, const bf16* __restrict__ Bt,
    void* __restrict__ Cout, const float* __restrict__ bias,
    int M, int N, int K)
{
  __shared__ char smem[32768];
  char* As = smem;
  char* Bs = smem + 16384;
  const int tid = threadIdx.x;
  const int w = tid >> 6, l = tid & 63;
  const int lg = l >> 4, ll = l & 15;

  // XCD-aware swizzle: XCD k gets a contiguous chunk of work indices
  const int nwg = gridDim.x * gridDim.y;
  int wg = blockIdx.y * gridDim.x + blockIdx.x;
  wg = (wg & 7) * (nwg >> 3) + (wg >> 3);
  const int n0 = (wg % gridDim.x) * 128;
  const int m0 = (wg / gridDim.x) * 128;
  const int wr = w >> 1, wc = w & 1;

  f32x4 acc[4][4];
  for (int i = 0; i < 4; ++i) for (int j = 0; j < 4; ++j) acc[i][j] = (f32x4){0.f,0.f,0.f,0.f};

  for (int k0 = 0; k0 < K; k0 += 64) {
    for (int t = 0; t < 4; ++t) {
      int seg = w*4 + t;
      int row = seg*8 + (l >> 3);
      int cb  = (l & 7) * 8;
      load_lds16(A  + (size_t)(m0 + row) * K + k0 + cb, As + seg*1024);
      load_lds16(Bt + (size_t)(n0 + row) * K + k0 + cb, Bs + seg*1024);
    }
    __syncthreads();
    for (int kc = 0; kc < 2; ++kc) {
      bf16x8 af[4], bfr[4];
      for (int ai = 0; ai < 4; ++ai)
        af[ai]  = *(const bf16x8*)(As + (wr*64 + ai*16 + ll)*128 + kc*64 + lg*16);
      for (int bj = 0; bj < 4; ++bj)
        bfr[bj] = *(const bf16x8*)(Bs + (wc*64 + bj*16 + ll)*128 + kc*64 + lg*16);
      for (int ai = 0; ai < 4; ++ai)
        for (int bj = 0; bj < 4; ++bj)
          acc[ai][bj] = MFMA(af[ai], bfr[bj], acc[ai][bj]);
    }
    __syncthreads();
  }

  for (int ai = 0; ai < 4; ++ai) {
    int row = m0 + wr*64 + ai*16 + lg*4;
    for (int bj = 0; bj < 4; ++bj) {
      int col = n0 + wc*64 + bj*16 + ll;
      float bv = bias[col];
      for (int r = 0; r < 4; ++r) {
        float v = acc[ai][bj][r] + bv;
        if constexpr (OUT_F32) ((float*)Cout)[(size_t)(row + r) * N + col] = v;
        else                   ((bf16*)Cout)[(size_t)(row + r) * N + col] = (bf16)v;
      }
    }
  }
}

// ---------------- RoPE ----------------

__global__ void rope_q(bf16* __restrict__ qkv, const float* __restrict__ fc, const float* __restrict__ fs) {
  int idx = blockIdx.x * 256 + threadIdx.x;
  int d = idx & 63, h = (idx >> 6) & 15, bt = idx >> 10;
  int t = bt & 2047;
  bf16* p = qkv + (size_t)bt * 2304 + h * 128 + 2 * d;
  float re = (float)p[0], im = (float)p[1];
  float c = fc[t*64 + d], s = fs[t*64 + d];
  p[0] = (bf16)(re * c - im * s);
  p[1] = (bf16)(re * s + im * c);
}

__global__ void rope_k(bf16* __restrict__ qkv, const float* __restrict__ fc, const float* __restrict__ fs) {
  int idx = blockIdx.x * 256 + threadIdx.x;
  int d = idx & 63, bt = idx >> 6;
  int t = bt & 2047;
  bf16* p = qkv + (size_t)bt * 2304 + 2048 + 2 * d;
  float re = (float)p[0], im = (float)p[1];
  float c = fc[t*64 + d], s = fs[t*64 + d];
  p[0] = (bf16)(re * c - im * s);
  p[1] = (bf16)(re * s + im * c);
}

// V cols of qkv -> v_t (B, 128, T)
__global__ void transpose_v(const bf16* __restrict__ qkv, bf16* __restrict__ vt) {
  __shared__ bf16 tl[32][33];
  int t0 = blockIdx.x * 32, d0 = blockIdx.y * 32, b = blockIdx.z;
  int tx = threadIdx.x, ty = threadIdx.y;
  for (int i = 0; i < 4; ++i)
    tl[ty + i*8][tx] = qkv[(size_t)(b*2048 + t0 + ty + i*8) * 2304 + 2176 + d0 + tx];
  __syncthreads();
  for (int i = 0; i < 4; ++i)
    vt[(size_t)(b*128 + d0 + ty + i*8) * 2048 + t0 + tx] = tl[tx][ty + i*8];
}

// ---------------- causal MQA flash attention ----------------
// grid (16 pairs, H, B); block p handles q-tiles x=p and x=31-p (64 rows each)
// -> uniform 17 KV-tiles (of 128) per block. 4 waves; wave w owns 16 q-rows.
// LDS 64KB: Ks[128][256B] + Vs[128][256B]; per-wave P overlays dead Ks region
// (K consumed by QK^T before P write; mid-tile barrier guards the overlay).

__global__ __launch_bounds__(256) void attn_kernel(
    const bf16* __restrict__ qkv, const bf16* __restrict__ vt, bf16* __restrict__ aout)
{
  constexpr int T = 2048, NQKV = 2304, D = 128;
  const int tid = threadIdx.x;
  const int w = tid >> 6, l = tid & 63;
  const int lg = l >> 4, ll = l & 15;
  const int h  = blockIdx.y;
  const int b  = blockIdx.z;

  __shared__ char smem[65536];
  char* Ks = smem;                 // [128 rows][256B], swz: byte ^= (row&7)<<4
  char* Vs = smem + 32768;         // [128 rows][256B], swz: byte ^= (row&7)<<4
  char* Ps = smem + w*8192;        // overlay on Ks: per-wave [16][256B], swz ^(prow&7)<<4

  const size_t qkvb = (size_t)b * T * NQKV;
  const float scale = 0.08838834764831845f;   // 1/sqrt(128)

  for (int half = 0; half < 2; ++half) {
    const int x  = half ? (31 - blockIdx.x) : blockIdx.x;
    const int q0 = x * 64;

    // Q fragments for this wave's 16 rows
    bf16x8 qf[4];
    {
      int row = q0 + w*16 + ll;
      const bf16* qrow = qkv + qkvb + (size_t)row * NQKV + h * D;
      for (int kc = 0; kc < 4; ++kc)
        qf[kc] = *(const bf16x8*)(qrow + kc*32 + lg*8);
    }

    f32x4 acc[8];
    for (int dt = 0; dt < 8; ++dt) acc[dt] = (f32x4){0.f,0.f,0.f,0.f};
    float mx[4], sm[4];
    for (int r = 0; r < 4; ++r) { mx[r] = -3e38f; sm[r] = 0.f; }

    for (int j0 = 0; j0 <= q0; j0 += 128) {
      // stage K tile [128][256B] via global_load_lds, pre-swizzled source
      for (int t = 0; t < 8; ++t) {
        int seg = w*8 + t;                 // 32 segs x 1KB
        int row = seg*4 + (l >> 4);        // 4 rows (256B) per seg
        int gb  = ((l & 15) * 16) ^ ((row & 7) << 4);
        load_lds16(qkv + qkvb + (size_t)(j0 + row) * NQKV + 2048 + (gb >> 1), Ks + seg*1024);
      }
      // stage Vt tile [128][128] via global_load_lds, pre-swizzled source
      for (int t = 0; t < 8; ++t) {
        int seg = w*8 + t;
        int row = seg*4 + (l >> 4);
        int gb  = ((l & 15) * 16) ^ ((row & 7) << 4);
        load_lds16(vt + (size_t)(b*D + row) * T + j0 + (gb >> 1), Vs + seg*1024);
      }
      __syncthreads();

      // QK^T: S[16 rows][128 cols]
      f32x4 sv[8];
      __builtin_amdgcn_s_setprio(1);
      for (int jt = 0; jt < 8; ++jt) {
        int row = jt*16 + ll;
        f32x4 s = (f32x4){0.f,0.f,0.f,0.f};
        for (int kc = 0; kc < 4; ++kc) {
          bf16x8 kf = *(const bf16x8*)(Ks + row*256 + ((kc*64 + lg*16) ^ ((row & 7) << 4)));
          s = MFMA(qf[kc], kf, s);
        }
        sv[jt] = s;
      }
      __builtin_amdgcn_s_setprio(0);

      __syncthreads();   // all waves done reading Ks -> P may overlay it

      // scale (+ causal mask only when tile straddles the diagonal)
      if (j0 + 127 > q0) {
        int i_g = q0 + w*16 + lg*4;
        for (int jt = 0; jt < 8; ++jt) {
          int j_g = j0 + jt*16 + ll;
          for (int r = 0; r < 4; ++r) {
            float v = sv[jt][r] * scale;
            sv[jt][r] = (j_g <= i_g + r) ? v : -1e9f;
          }
        }
      } else {
        for (int jt = 0; jt < 8; ++jt)
          for (int r = 0; r < 4; ++r)
            sv[jt][r] *= scale;
      }

      // online softmax with defer-max (THR=8)
      for (int r = 0; r < 4; ++r) {
        float tm = -3e38f;
        for (int jt = 0; jt < 8; ++jt) tm = fmaxf(tm, sv[jt][r]);
        tm = fmaxf(tm, __shfl_xor(tm, 1));
        tm = fmaxf(tm, __shfl_xor(tm, 2));
        tm = fmaxf(tm, __shfl_xor(tm, 4));
        tm = fmaxf(tm, __shfl_xor(tm, 8));
        float mo = mx[r];
        if (!__all(tm - mo <= 8.f)) {
          float mn = fmaxf(mo, tm);
          float fac = __expf(mo - mn);
          mx[r] = mn; sm[r] *= fac;
          for (int dt = 0; dt < 8; ++dt) acc[dt][r] *= fac;
          mo = mn;
        }
        float ps = 0.f;
        for (int jt = 0; jt < 8; ++jt) {
          float p = __expf(sv[jt][r] - mo);
          sv[jt][r] = p;
          ps += p;
        }
        ps += __shfl_xor(ps, 1);
        ps += __shfl_xor(ps, 2);
        ps += __shfl_xor(ps, 4);
        ps += __shfl_xor(ps, 8);
        sm[r] += ps;
      }

      // P -> per-wave LDS (bf16, swizzled, overlaid on Ks)
      for (int jt = 0; jt < 8; ++jt)
        for (int r = 0; r < 4; ++r) {
          int prow = lg*4 + r;
          *(bf16*)(Ps + prow*256 + (((jt*16 + ll)*2) ^ ((prow & 7) << 4))) = (bf16)sv[jt][r];
        }
      asm volatile("s_waitcnt lgkmcnt(0)" ::: "memory");

      // PV: acc[16 rows][128 d] += P[16][128] @ V^T
      bf16x8 pa[4];
      for (int c = 0; c < 4; ++c)
        pa[c] = *(const bf16x8*)(Ps + ll*256 + ((c*64 + lg*16) ^ ((ll & 7) << 4)));
      __builtin_amdgcn_s_setprio(1);
      for (int dt = 0; dt < 8; ++dt) {
        int row = dt*16 + ll;
        for (int c = 0; c < 4; ++c) {
          bf16x8 vf = *(const bf16x8*)(Vs + row*256 + ((c*64 + lg*16) ^ ((row & 7) << 4)));
          acc[dt] = MFMA(pa[c], vf, acc[dt]);
        }
      }
      __builtin_amdgcn_s_setprio(0);
      __syncthreads();
    }

    // normalize + write
    for (int dt = 0; dt < 8; ++dt) {
      int col = h*D + dt*16 + ll;
      for (int r = 0; r < 4; ++r) {
        int row = q0 + w*16 + lg*4 + r;
        float v = acc[dt][r] / sm[r];
        aout[(size_t)(b*T + row) * 2048 + col] = (bf16)v;
      }
    }
  }
}

// ---------------- launch ----------------

extern "C" void kernel_launch(void* const* d_in, const int* in_sizes, int n_in,
                              void* d_out, int out_size, void* d_ws, size_t ws_size,
                              hipStream_t stream) {
  const float* x  = (const float*)d_in[0];
  const float* fc = (const float*)d_in[1];
  const float* fs = (const float*)d_in[2];
  const float* wq = (const float*)d_in[4];
  const float* qb = (const float*)d_in[5];
  const float* wk = (const float*)d_in[6];
  const float* kb = (const float*)d_in[7];
  const float* wv = (const float*)d_in[8];
  const float* vb = (const float*)d_in[9];
  const float* wo = (const float*)d_in[10];
  const float* ob = (const float*)d_in[11];

  char* ws = (char*)d_ws;
  bf16*  x_bf   = (bf16*)(ws);                       // 16 MiB (reused as attn_out)
  bf16*  qkv    = (bf16*)(ws + 16777216);            // 18 MiB  (4096 x 2304)
  bf16*  wqkv_t = (bf16*)(ws + 35651584);            // 9 MiB   (2304 x 2048)
  bf16*  wo_t   = (bf16*)(ws + 45088768);            // 8 MiB   (2048 x 2048)
  bf16*  v_t    = (bf16*)(ws + 53477376);            // 1 MiB   (2 x 128 x 2048)
  float* qkvb   = (float*)(ws + 54525952);           // 9216 B
  bf16*  a_out  = x_bf;

  cvt_bf16<<<8192, 256, 0, stream>>>(x, x_bf, 2097152);
  transpose_w<<<dim3(64,64), dim3(32,8), 0, stream>>>(wq, wqkv_t, 2048);
  transpose_w<<<dim3(4,64),  dim3(32,8), 0, stream>>>(wk, wqkv_t + (size_t)2048*2048, 128);
  transpose_w<<<dim3(4,64),  dim3(32,8), 0, stream>>>(wv, wqkv_t + (size_t)2176*2048, 128);
  transpose_w<<<dim3(64,64), dim3(32,8), 0, stream>>>(wo, wo_t, 2048);
  concat_bias<<<9, 256, 0, stream>>>(qb, kb, vb, qkvb);

  gemm_bt<false><<<dim3(18,32), 256, 0, stream>>>(x_bf, wqkv_t, qkv, qkvb, 4096, 2304, 2048);

  rope_q<<<16384, 256, 0, stream>>>(qkv, fc, fs);
  rope_k<<<1024, 256, 0, stream>>>(qkv, fc, fs);
  transpose_v<<<dim3(64,4,2), dim3(32,8), 0, stream>>>(qkv, v_t);

  attn_kernel<<<dim3(16,16,2), 256, 0, stream>>>(qkv, v_t, a_out);

  gemm_bt<true><<<dim3(16,32), 256, 0, stream>>>(a_out, wo_t, d_out, ob, 4096, 2048, 2048);
}

// Round 11
// 389.239 us; speedup vs baseline: 1.1049x; 1.1049x over previous
//
#include <hip/hip_runtime.h>
#include <hip/hip_bf16.h>

typedef __bf16 bf16;
typedef __bf16 bf16x4 __attribute__((ext_vector_type(4)));
typedef __bf16 bf16x8 __attribute__((ext_vector_type(8)));
typedef float  f32x4  __attribute__((ext_vector_type(4)));

#define MFMA(a,b,c) __builtin_amdgcn_mfma_f32_16x16x32_bf16(a,b,c,0,0,0)

__device__ __forceinline__ void load_lds16(const void* gptr, void* lptr) {
  __builtin_amdgcn_global_load_lds(
      (const __attribute__((address_space(1))) void*)gptr,
      (__attribute__((address_space(3))) void*)lptr, 16, 0, 0);
}

// ---------------- conversion / transpose kernels ----------------

__global__ void cvt_bf16(const float* __restrict__ in, bf16* __restrict__ out, int n4) {
  int i = blockIdx.x * blockDim.x + threadIdx.x;
  if (i >= n4) return;
  float4 v = ((const float4*)in)[i];
  bf16x4 o = { (bf16)v.x, (bf16)v.y, (bf16)v.z, (bf16)v.w };
  ((bf16x4*)out)[i] = o;
}

// src: [2048][ncols] f32 ; dst: [ncols][2048] bf16 (row stride 2048)
__global__ void transpose_w(const float* __restrict__ src, bf16* __restrict__ dst, int ncols) {
  __shared__ float tl[32][33];
  int n0 = blockIdx.x * 32, k0 = blockIdx.y * 32;
  int tx = threadIdx.x, ty = threadIdx.y;
  for (int i = 0; i < 4; ++i)
    tl[ty + i*8][tx] = src[(size_t)(k0 + ty + i*8) * ncols + n0 + tx];
  __syncthreads();
  for (int i = 0; i < 4; ++i)
    dst[(size_t)(n0 + ty + i*8) * 2048 + k0 + tx] = (bf16)tl[tx][ty + i*8];
}

__global__ void concat_bias(const float* __restrict__ qb, const float* __restrict__ kb,
                            const float* __restrict__ vb, float* __restrict__ o) {
  int i = blockIdx.x * 256 + threadIdx.x;
  if (i >= 2304) return;
  o[i] = (i < 2048) ? qb[i] : (i < 2176 ? kb[i - 2048] : vb[i - 2176]);
}

// ---------------- GEMM: C[M,N] = A[M,K] @ Bt[N,K]^T + bias ----------------

template<bool OUT_F32>
__global__ __launch_bounds__(256) void gemm_bt(
    const bf16* __restrict__ A, const bf16* __restrict__ Bt,
    void* __restrict__ Cout, const float* __restrict__ bias,
    int M, int N, int K)
{
  __shared__ char smem[32768];
  char* As = smem;
  char* Bs = smem + 16384;
  const int tid = threadIdx.x;
  const int w = tid >> 6, l = tid & 63;
  const int lg = l >> 4, ll = l & 15;
  const int n0 = blockIdx.x * 128, m0 = blockIdx.y * 128;
  const int wr = w >> 1, wc = w & 1;

  f32x4 acc[4][4];
  for (int i = 0; i < 4; ++i) for (int j = 0; j < 4; ++j) acc[i][j] = (f32x4){0.f,0.f,0.f,0.f};

  for (int k0 = 0; k0 < K; k0 += 64) {
    for (int t = 0; t < 4; ++t) {
      int seg = w*4 + t;
      int row = seg*8 + (l >> 3);
      int cb  = (l & 7) * 8;
      load_lds16(A  + (size_t)(m0 + row) * K + k0 + cb, As + seg*1024);
      load_lds16(Bt + (size_t)(n0 + row) * K + k0 + cb, Bs + seg*1024);
    }
    __syncthreads();
    for (int kc = 0; kc < 2; ++kc) {
      bf16x8 af[4], bfr[4];
      for (int ai = 0; ai < 4; ++ai)
        af[ai]  = *(const bf16x8*)(As + (wr*64 + ai*16 + ll)*128 + kc*64 + lg*16);
      for (int bj = 0; bj < 4; ++bj)
        bfr[bj] = *(const bf16x8*)(Bs + (wc*64 + bj*16 + ll)*128 + kc*64 + lg*16);
      for (int ai = 0; ai < 4; ++ai)
        for (int bj = 0; bj < 4; ++bj)
          acc[ai][bj] = MFMA(af[ai], bfr[bj], acc[ai][bj]);
    }
    __syncthreads();
  }

  for (int ai = 0; ai < 4; ++ai) {
    int row = m0 + wr*64 + ai*16 + lg*4;
    for (int bj = 0; bj < 4; ++bj) {
      int col = n0 + wc*64 + bj*16 + ll;
      float bv = bias[col];
      for (int r = 0; r < 4; ++r) {
        float v = acc[ai][bj][r] + bv;
        if constexpr (OUT_F32) ((float*)Cout)[(size_t)(row + r) * N + col] = v;
        else                   ((bf16*)Cout)[(size_t)(row + r) * N + col] = (bf16)v;
      }
    }
  }
}

// ---------------- RoPE ----------------

__global__ void rope_q(bf16* __restrict__ qkv, const float* __restrict__ fc, const float* __restrict__ fs) {
  int idx = blockIdx.x * 256 + threadIdx.x;
  int d = idx & 63, h = (idx >> 6) & 15, bt = idx >> 10;
  int t = bt & 2047;
  bf16* p = qkv + (size_t)bt * 2304 + h * 128 + 2 * d;
  float re = (float)p[0], im = (float)p[1];
  float c = fc[t*64 + d], s = fs[t*64 + d];
  p[0] = (bf16)(re * c - im * s);
  p[1] = (bf16)(re * s + im * c);
}

__global__ void rope_k(bf16* __restrict__ qkv, const float* __restrict__ fc, const float* __restrict__ fs) {
  int idx = blockIdx.x * 256 + threadIdx.x;
  int d = idx & 63, bt = idx >> 6;
  int t = bt & 2047;
  bf16* p = qkv + (size_t)bt * 2304 + 2048 + 2 * d;
  float re = (float)p[0], im = (float)p[1];
  float c = fc[t*64 + d], s = fs[t*64 + d];
  p[0] = (bf16)(re * c - im * s);
  p[1] = (bf16)(re * s + im * c);
}

// V cols of qkv -> v_t (B, 128, T)
__global__ void transpose_v(const bf16* __restrict__ qkv, bf16* __restrict__ vt) {
  __shared__ bf16 tl[32][33];
  int t0 = blockIdx.x * 32, d0 = blockIdx.y * 32, b = blockIdx.z;
  int tx = threadIdx.x, ty = threadIdx.y;
  for (int i = 0; i < 4; ++i)
    tl[ty + i*8][tx] = qkv[(size_t)(b*2048 + t0 + ty + i*8) * 2304 + 2176 + d0 + tx];
  __syncthreads();
  for (int i = 0; i < 4; ++i)
    vt[(size_t)(b*128 + d0 + ty + i*8) * 2048 + t0 + tx] = tl[tx][ty + i*8];
}

// ---------------- causal MQA flash attention ----------------
// R1 structure (verified 102us): KVBLK=64, 40KB LDS, 4 blocks/CU.
// + T13 defer-max (THR=8), T5 setprio around MFMA clusters.

__global__ __launch_bounds__(256) void attn_kernel(
    const bf16* __restrict__ qkv, const bf16* __restrict__ vt, bf16* __restrict__ aout)
{
  constexpr int T = 2048, NQKV = 2304, D = 128;
  const int tid = threadIdx.x;
  const int w = tid >> 6, l = tid & 63;
  const int lg = l >> 4, ll = l & 15;
  const int h  = blockIdx.y;
  const int b  = blockIdx.z;

  __shared__ char smem[16384 + 16384 + 8192];
  char* Ks = smem;                    // [64 rows][256B], swz: byte ^= (row&7)<<4
  char* Vs = smem + 16384;            // [128 rows][128B], swz: byte ^= (row&7)<<4
  char* Ps = smem + 32768 + w*2048;   // per-wave [16 rows][128B], swz: byte ^= (row&7)<<4

  const size_t qkvb = (size_t)b * T * NQKV;
  const float scale = 0.08838834764831845f;   // 1/sqrt(128)

  for (int half = 0; half < 2; ++half) {
    const int x  = half ? (31 - blockIdx.x) : blockIdx.x;
    const int q0 = x * 64;

    // Q fragments for this wave's 16 rows
    bf16x8 qf[4];
    {
      int row = q0 + w*16 + ll;
      const bf16* qrow = qkv + qkvb + (size_t)row * NQKV + h * D;
      for (int kc = 0; kc < 4; ++kc)
        qf[kc] = *(const bf16x8*)(qrow + kc*32 + lg*8);
    }

    f32x4 acc[8];
    for (int dt = 0; dt < 8; ++dt) acc[dt] = (f32x4){0.f,0.f,0.f,0.f};
    float mx[4], sm[4];
    for (int r = 0; r < 4; ++r) { mx[r] = -3e38f; sm[r] = 0.f; }

    for (int j0 = 0; j0 <= q0; j0 += 64) {
      // stage K tile [64][128] via global_load_lds, pre-swizzled source
      for (int t = 0; t < 4; ++t) {
        int seg = w*4 + t;                 // 16 segs x 1KB
        int row = seg*4 + (l >> 4);        // 4 rows (256B) per seg
        int gcol = (((l & 15) * 16) ^ ((row & 7) << 4)) >> 1;
        load_lds16(qkv + qkvb + (size_t)(j0 + row) * NQKV + 2048 + gcol, Ks + seg*1024);
      }
      // stage Vt tile [128][64] via global_load_lds, pre-swizzled source
      for (int t = 0; t < 4; ++t) {
        int seg = w*4 + t;
        int row = seg*8 + (l >> 3);        // 8 rows (128B) per seg
        int gcol = (((l & 7) * 16) ^ ((row & 7) << 4)) >> 1;
        load_lds16(vt + (size_t)(b*D + row) * T + j0 + gcol, Vs + seg*1024);
      }
      __syncthreads();

      // QK^T: S[16 rows][64 cols]
      f32x4 sv[4];
      __builtin_amdgcn_s_setprio(1);
      for (int jt = 0; jt < 4; ++jt) {
        int row = jt*16 + ll;
        f32x4 s = (f32x4){0.f,0.f,0.f,0.f};
        for (int kc = 0; kc < 4; ++kc) {
          bf16x8 kf = *(const bf16x8*)(Ks + row*256 + ((kc*64 + lg*16) ^ ((row & 7) << 4)));
          s = MFMA(qf[kc], kf, s);
        }
        sv[jt] = s;
      }
      __builtin_amdgcn_s_setprio(0);

      // scale (+ causal mask only on the diagonal tile j0==q0)
      if (j0 == q0) {
        for (int jt = 0; jt < 4; ++jt)
          for (int r = 0; r < 4; ++r) {
            int i = w*16 + lg*4 + r;            // row within q-tile
            int j = jt*16 + ll;                 // col within kv-tile
            float v = sv[jt][r] * scale;
            sv[jt][r] = (j <= i) ? v : -1e9f;
          }
      } else {
        for (int jt = 0; jt < 4; ++jt)
          for (int r = 0; r < 4; ++r)
            sv[jt][r] *= scale;
      }

      // online softmax with defer-max (THR=8)
      for (int r = 0; r < 4; ++r) {
        float tm = fmaxf(fmaxf(sv[0][r], sv[1][r]), fmaxf(sv[2][r], sv[3][r]));
        tm = fmaxf(tm, __shfl_xor(tm, 1));
        tm = fmaxf(tm, __shfl_xor(tm, 2));
        tm = fmaxf(tm, __shfl_xor(tm, 4));
        tm = fmaxf(tm, __shfl_xor(tm, 8));
        float mo = mx[r];
        if (!__all(tm - mo <= 8.f)) {
          float mn = fmaxf(mo, tm);
          float fac = __expf(mo - mn);
          mx[r] = mn; sm[r] *= fac;
          for (int dt = 0; dt < 8; ++dt) acc[dt][r] *= fac;
          mo = mn;
        }
        float ps = 0.f;
        for (int jt = 0; jt < 4; ++jt) {
          float p = __expf(sv[jt][r] - mo);
          sv[jt][r] = p;
          ps += p;
        }
        ps += __shfl_xor(ps, 1);
        ps += __shfl_xor(ps, 2);
        ps += __shfl_xor(ps, 4);
        ps += __shfl_xor(ps, 8);
        sm[r] += ps;
      }

      // P -> per-wave LDS (bf16, swizzled)
      for (int jt = 0; jt < 4; ++jt)
        for (int r = 0; r < 4; ++r) {
          int prow = lg*4 + r;
          *(bf16*)(Ps + prow*128 + (((jt*16 + ll)*2) ^ ((prow & 7) << 4))) = (bf16)sv[jt][r];
        }
      asm volatile("s_waitcnt lgkmcnt(0)" ::: "memory");

      // PV: acc[16 rows][128 d] += P[16][64] @ V^T
      bf16x8 pa[2];
      for (int c = 0; c < 2; ++c)
        pa[c] = *(const bf16x8*)(Ps + ll*128 + ((c*64 + lg*16) ^ ((ll & 7) << 4)));
      __builtin_amdgcn_s_setprio(1);
      for (int dt = 0; dt < 8; ++dt) {
        int row = dt*16 + ll;
        for (int c = 0; c < 2; ++c) {
          bf16x8 vf = *(const bf16x8*)(Vs + row*128 + ((c*64 + lg*16) ^ ((row & 7) << 4)));
          acc[dt] = MFMA(pa[c], vf, acc[dt]);
        }
      }
      __builtin_amdgcn_s_setprio(0);
      __syncthreads();
    }

    // normalize + write
    for (int dt = 0; dt < 8; ++dt) {
      int col = h*D + dt*16 + ll;
      for (int r = 0; r < 4; ++r) {
        int row = q0 + w*16 + lg*4 + r;
        float v = acc[dt][r] / sm[r];
        aout[(size_t)(b*T + row) * 2048 + col] = (bf16)v;
      }
    }
  }
}

// ---------------- launch ----------------

extern "C" void kernel_launch(void* const* d_in, const int* in_sizes, int n_in,
                              void* d_out, int out_size, void* d_ws, size_t ws_size,
                              hipStream_t stream) {
  const float* x  = (const float*)d_in[0];
  const float* fc = (const float*)d_in[1];
  const float* fs = (const float*)d_in[2];
  const float* wq = (const float*)d_in[4];
  const float* qb = (const float*)d_in[5];
  const float* wk = (const float*)d_in[6];
  const float* kb = (const float*)d_in[7];
  const float* wv = (const float*)d_in[8];
  const float* vb = (const float*)d_in[9];
  const float* wo = (const float*)d_in[10];
  const float* ob = (const float*)d_in[11];

  char* ws = (char*)d_ws;
  bf16*  x_bf   = (bf16*)(ws);                       // 16 MiB (reused as attn_out)
  bf16*  qkv    = (bf16*)(ws + 16777216);            // 18 MiB  (4096 x 2304)
  bf16*  wqkv_t = (bf16*)(ws + 35651584);            // 9 MiB   (2304 x 2048)
  bf16*  wo_t   = (bf16*)(ws + 45088768);            // 8 MiB   (2048 x 2048)
  bf16*  v_t    = (bf16*)(ws + 53477376);            // 1 MiB   (2 x 128 x 2048)
  float* qkvb   = (float*)(ws + 54525952);           // 9216 B
  bf16*  a_out  = x_bf;

  cvt_bf16<<<8192, 256, 0, stream>>>(x, x_bf, 2097152);
  transpose_w<<<dim3(64,64), dim3(32,8), 0, stream>>>(wq, wqkv_t, 2048);
  transpose_w<<<dim3(4,64),  dim3(32,8), 0, stream>>>(wk, wqkv_t + (size_t)2048*2048, 128);
  transpose_w<<<dim3(4,64),  dim3(32,8), 0, stream>>>(wv, wqkv_t + (size_t)2176*2048, 128);
  transpose_w<<<dim3(64,64), dim3(32,8), 0, stream>>>(wo, wo_t, 2048);
  concat_bias<<<9, 256, 0, stream>>>(qb, kb, vb, qkvb);

  gemm_bt<false><<<dim3(18,32), 256, 0, stream>>>(x_bf, wqkv_t, qkv, qkvb, 4096, 2304, 2048);

  rope_q<<<16384, 256, 0, stream>>>(qkv, fc, fs);
  rope_k<<<1024, 256, 0, stream>>>(qkv, fc, fs);
  transpose_v<<<dim3(64,4,2), dim3(32,8), 0, stream>>>(qkv, v_t);

  attn_kernel<<<dim3(16,16,2), 256, 0, stream>>>(qkv, v_t, a_out);

  gemm_bt<true><<<dim3(16,32), 256, 0, stream>>>(a_out, wo_t, d_out, ob, 4096, 2048, 2048);
}

// Round 13
// 361.105 us; speedup vs baseline: 1.1910x; 1.0779x over previous
//
#include <hip/hip_runtime.h>
#include <hip/hip_bf16.h>

typedef __bf16 bf16;
typedef __bf16 bf16x4 __attribute__((ext_vector_type(4)));
typedef __bf16 bf16x8 __attribute__((ext_vector_type(8)));
typedef float  f32x4  __attribute__((ext_vector_type(4)));

#define MFMA(a,b,c) __builtin_amdgcn_mfma_f32_16x16x32_bf16(a,b,c,0,0,0)

__device__ __forceinline__ void load_lds16(const void* gptr, void* lptr) {
  __builtin_amdgcn_global_load_lds(
      (const __attribute__((address_space(1))) void*)gptr,
      (__attribute__((address_space(3))) void*)lptr, 16, 0, 0);
}

// ---------------- conversion / transpose kernels ----------------

__global__ void cvt_bf16(const float* __restrict__ in, bf16* __restrict__ out, int n4) {
  int i = blockIdx.x * blockDim.x + threadIdx.x;
  if (i >= n4) return;
  float4 v = ((const float4*)in)[i];
  bf16x4 o = { (bf16)v.x, (bf16)v.y, (bf16)v.z, (bf16)v.w };
  ((bf16x4*)out)[i] = o;
}

// src: [2048][ncols] f32 ; dst: [ncols][2048] bf16 (row stride 2048)
__global__ void transpose_w(const float* __restrict__ src, bf16* __restrict__ dst, int ncols) {
  __shared__ float tl[32][33];
  int n0 = blockIdx.x * 32, k0 = blockIdx.y * 32;
  int tx = threadIdx.x, ty = threadIdx.y;
  for (int i = 0; i < 4; ++i)
    tl[ty + i*8][tx] = src[(size_t)(k0 + ty + i*8) * ncols + n0 + tx];
  __syncthreads();
  for (int i = 0; i < 4; ++i)
    dst[(size_t)(n0 + ty + i*8) * 2048 + k0 + tx] = (bf16)tl[tx][ty + i*8];
}

__global__ void concat_bias(const float* __restrict__ qb, const float* __restrict__ kb,
                            const float* __restrict__ vb, float* __restrict__ o) {
  int i = blockIdx.x * 256 + threadIdx.x;
  if (i >= 2304) return;
  o[i] = (i < 2048) ? qb[i] : (i < 2176 ? kb[i - 2048] : vb[i - 2176]);
}

// ---------------- GEMM 256x256: C[M,N] = A[M,K] @ Bt[N,K]^T + bias --------
// 8 waves (2M x 4N), BK=64, 2-buffer pipeline with counted vmcnt (T3/T4),
// (row&7)<<4 LDS swizzle via pre-swizzled global source (T2), XCD swizzle (T1).
// Race-safety: STAGE(kt+1) writes buf[(kt+1)&1], whose previous tile (kt-1)
// was fully consumed before the prior closing barrier; reads of tile kt are
// gated by vmcnt(8)+barrier (8 = this wave's loads for tile kt+1 in flight).

template<bool OUT_F32>
__global__ __launch_bounds__(512) void gemm_bt256(
    const bf16* __restrict__ A, const bf16* __restrict__ Bt,
    void* __restrict__ Cout, const float* __restrict__ bias,
    int M, int N, int K)
{
  __shared__ char smem[131072];     // 2 x (A 32KB + B 32KB)
  const int tid = threadIdx.x;
  const int w = tid >> 6, l = tid & 63;
  const int lg = l >> 4, ll = l & 15;
  const int wm = w >> 2, wn = w & 3;

  // XCD-aware swizzle: physical bid%8 = XCD; each XCD gets contiguous works
  const int nwg = gridDim.x * gridDim.y;
  int bid = blockIdx.y * gridDim.x + blockIdx.x;
  int work = (bid & 7) * (nwg >> 3) + (bid >> 3);
  const int n0 = (work % gridDim.x) * 256;
  const int m0 = (work / gridDim.x) * 256;

  const int nt = K >> 6;

  f32x4 acc[8][4];
  for (int i = 0; i < 8; ++i) for (int j = 0; j < 4; ++j) acc[i][j] = (f32x4){0.f,0.f,0.f,0.f};

  // stage tile kt into buffer buf: A[256][64] + Bt[256][64], swizzled source
  auto STAGE = [&](int buf, int kt) {
    char* As = smem + buf * 65536;
    char* Bs = As + 32768;
    int k0 = kt * 64;
    for (int t = 0; t < 4; ++t) {
      int seg = w * 4 + t;                    // 32 segs x 1KB each
      int row = seg * 8 + (l >> 3);           // 8 rows (128B) per seg
      int cb  = ((l & 7) * 16) ^ ((row & 7) << 4);
      load_lds16(A  + (size_t)(m0 + row) * K + k0 + (cb >> 1), As + seg * 1024);
      load_lds16(Bt + (size_t)(n0 + row) * K + k0 + (cb >> 1), Bs + seg * 1024);
    }
  };

  STAGE(0, 0);

  for (int kt = 0; kt < nt; ++kt) {
    if (kt + 1 < nt) {
      STAGE((kt + 1) & 1, kt + 1);
      asm volatile("s_waitcnt vmcnt(8)" ::: "memory");   // tile kt landed (per-wave)
    } else {
      asm volatile("s_waitcnt vmcnt(0)" ::: "memory");
    }
    __builtin_amdgcn_s_barrier();
    const char* As = smem + (kt & 1) * 65536;
    const char* Bs = As + 32768;
    for (int kc = 0; kc < 2; ++kc) {
      bf16x8 af[8], bfr[4];
      for (int ai = 0; ai < 8; ++ai) {
        int row = wm * 128 + ai * 16 + ll;
        af[ai] = *(const bf16x8*)(As + row * 128 + ((kc * 64 + lg * 16) ^ ((row & 7) << 4)));
      }
      for (int bj = 0; bj < 4; ++bj) {
        int row = wn * 64 + bj * 16 + ll;
        bfr[bj] = *(const bf16x8*)(Bs + row * 128 + ((kc * 64 + lg * 16) ^ ((row & 7) << 4)));
      }
      for (int ai = 0; ai < 8; ++ai)
        for (int bj = 0; bj < 4; ++bj)
          acc[ai][bj] = MFMA(af[ai], bfr[bj], acc[ai][bj]);
    }
    __builtin_amdgcn_s_barrier();
  }

  for (int ai = 0; ai < 8; ++ai) {
    int row = m0 + wm * 128 + ai * 16 + lg * 4;
    for (int bj = 0; bj < 4; ++bj) {
      int col = n0 + wn * 64 + bj * 16 + ll;
      float bv = bias[col];
      for (int r = 0; r < 4; ++r) {
        float v = acc[ai][bj][r] + bv;
        if constexpr (OUT_F32) ((float*)Cout)[(size_t)(row + r) * N + col] = v;
        else                   ((bf16*)Cout)[(size_t)(row + r) * N + col] = (bf16)v;
      }
    }
  }
}

// ---------------- RoPE ----------------

__global__ void rope_q(bf16* __restrict__ qkv, const float* __restrict__ fc, const float* __restrict__ fs) {
  int idx = blockIdx.x * 256 + threadIdx.x;
  int d = idx & 63, h = (idx >> 6) & 15, bt = idx >> 10;
  int t = bt & 2047;
  bf16* p = qkv + (size_t)bt * 2304 + h * 128 + 2 * d;
  float re = (float)p[0], im = (float)p[1];
  float c = fc[t*64 + d], s = fs[t*64 + d];
  p[0] = (bf16)(re * c - im * s);
  p[1] = (bf16)(re * s + im * c);
}

__global__ void rope_k(bf16* __restrict__ qkv, const float* __restrict__ fc, const float* __restrict__ fs) {
  int idx = blockIdx.x * 256 + threadIdx.x;
  int d = idx & 63, bt = idx >> 6;
  int t = bt & 2047;
  bf16* p = qkv + (size_t)bt * 2304 + 2048 + 2 * d;
  float re = (float)p[0], im = (float)p[1];
  float c = fc[t*64 + d], s = fs[t*64 + d];
  p[0] = (bf16)(re * c - im * s);
  p[1] = (bf16)(re * s + im * c);
}

// V cols of qkv -> v_t (B, 128, T)
__global__ void transpose_v(const bf16* __restrict__ qkv, bf16* __restrict__ vt) {
  __shared__ bf16 tl[32][33];
  int t0 = blockIdx.x * 32, d0 = blockIdx.y * 32, b = blockIdx.z;
  int tx = threadIdx.x, ty = threadIdx.y;
  for (int i = 0; i < 4; ++i)
    tl[ty + i*8][tx] = qkv[(size_t)(b*2048 + t0 + ty + i*8) * 2304 + 2176 + d0 + tx];
  __syncthreads();
  for (int i = 0; i < 4; ++i)
    vt[(size_t)(b*128 + d0 + ty + i*8) * 2048 + t0 + tx] = tl[tx][ty + i*8];
}

// ---------------- causal MQA flash attention (R7-verified, 102us) ----------
// grid (16 pairs, H, B); block p handles q-tiles x=p and x=31-p (64 rows each)
// -> uniform 33 KV-tiles (of 64) per block. 4 waves; wave w owns 16 q-rows.

__global__ __launch_bounds__(256) void attn_kernel(
    const bf16* __restrict__ qkv, const bf16* __restrict__ vt, bf16* __restrict__ aout)
{
  constexpr int T = 2048, NQKV = 2304, D = 128;
  const int tid = threadIdx.x;
  const int w = tid >> 6, l = tid & 63;
  const int lg = l >> 4, ll = l & 15;
  const int h  = blockIdx.y;
  const int b  = blockIdx.z;

  __shared__ char smem[16384 + 16384 + 8192];
  char* Ks = smem;                    // [64 rows][256B], swz: byte ^= (row&7)<<4
  char* Vs = smem + 16384;            // [128 rows][128B], swz: byte ^= (row&7)<<4
  char* Ps = smem + 32768 + w*2048;   // per-wave [16 rows][128B], swz: byte ^= (row&7)<<4

  const size_t qkvb = (size_t)b * T * NQKV;
  const float scale = 0.08838834764831845f;   // 1/sqrt(128)

  for (int half = 0; half < 2; ++half) {
    const int x  = half ? (31 - blockIdx.x) : blockIdx.x;
    const int q0 = x * 64;

    // Q fragments for this wave's 16 rows
    bf16x8 qf[4];
    {
      int row = q0 + w*16 + ll;
      const bf16* qrow = qkv + qkvb + (size_t)row * NQKV + h * D;
      for (int kc = 0; kc < 4; ++kc)
        qf[kc] = *(const bf16x8*)(qrow + kc*32 + lg*8);
    }

    f32x4 acc[8];
    for (int dt = 0; dt < 8; ++dt) acc[dt] = (f32x4){0.f,0.f,0.f,0.f};
    float mx[4], sm[4];
    for (int r = 0; r < 4; ++r) { mx[r] = -3e38f; sm[r] = 0.f; }

    for (int j0 = 0; j0 <= q0; j0 += 64) {
      // stage K tile [64][128] via global_load_lds, pre-swizzled source
      for (int t = 0; t < 4; ++t) {
        int seg = w*4 + t;                 // 16 segs x 1KB
        int row = seg*4 + (l >> 4);        // 4 rows (256B) per seg
        int gcol = (((l & 15) * 16) ^ ((row & 7) << 4)) >> 1;
        load_lds16(qkv + qkvb + (size_t)(j0 + row) * NQKV + 2048 + gcol, Ks + seg*1024);
      }
      // stage Vt tile [128][64] via global_load_lds, pre-swizzled source
      for (int t = 0; t < 4; ++t) {
        int seg = w*4 + t;
        int row = seg*8 + (l >> 3);        // 8 rows (128B) per seg
        int gcol = (((l & 7) * 16) ^ ((row & 7) << 4)) >> 1;
        load_lds16(vt + (size_t)(b*D + row) * T + j0 + gcol, Vs + seg*1024);
      }
      __syncthreads();

      // QK^T: S[16 rows][64 cols]
      f32x4 sv[4];
      for (int jt = 0; jt < 4; ++jt) {
        int row = jt*16 + ll;
        f32x4 s = (f32x4){0.f,0.f,0.f,0.f};
        for (int kc = 0; kc < 4; ++kc) {
          bf16x8 kf = *(const bf16x8*)(Ks + row*256 + ((kc*64 + lg*16) ^ ((row & 7) << 4)));
          s = MFMA(qf[kc], kf, s);
        }
        sv[jt] = s;
      }

      // scale (+ causal mask only on the diagonal tile j0==q0)
      if (j0 == q0) {
        for (int jt = 0; jt < 4; ++jt)
          for (int r = 0; r < 4; ++r) {
            int i = w*16 + lg*4 + r;            // row within q-tile
            int j = jt*16 + ll;                 // col within kv-tile
            float v = sv[jt][r] * scale;
            sv[jt][r] = (j <= i) ? v : -1e9f;
          }
      } else {
        for (int jt = 0; jt < 4; ++jt)
          for (int r = 0; r < 4; ++r)
            sv[jt][r] *= scale;
      }

      // online softmax (rows live in 16-lane groups)
      for (int r = 0; r < 4; ++r) {
        float tm = fmaxf(fmaxf(sv[0][r], sv[1][r]), fmaxf(sv[2][r], sv[3][r]));
        tm = fmaxf(tm, __shfl_xor(tm, 1));
        tm = fmaxf(tm, __shfl_xor(tm, 2));
        tm = fmaxf(tm, __shfl_xor(tm, 4));
        tm = fmaxf(tm, __shfl_xor(tm, 8));
        float mo = mx[r];
        float mn = fmaxf(mo, tm);
        mx[r] = mn;
        float fac = __expf(mo - mn);
        float ps = 0.f;
        for (int jt = 0; jt < 4; ++jt) {
          float p = __expf(sv[jt][r] - mn);
          sv[jt][r] = p;
          ps += p;
        }
        ps += __shfl_xor(ps, 1);
        ps += __shfl_xor(ps, 2);
        ps += __shfl_xor(ps, 4);
        ps += __shfl_xor(ps, 8);
        sm[r] = sm[r] * fac + ps;
        for (int dt = 0; dt < 8; ++dt) acc[dt][r] *= fac;
      }

      // P -> per-wave LDS (bf16, swizzled)
      for (int jt = 0; jt < 4; ++jt)
        for (int r = 0; r < 4; ++r) {
          int prow = lg*4 + r;
          *(bf16*)(Ps + prow*128 + (((jt*16 + ll)*2) ^ ((prow & 7) << 4))) = (bf16)sv[jt][r];
        }
      asm volatile("s_waitcnt lgkmcnt(0)" ::: "memory");

      // PV: acc[16 rows][128 d] += P[16][64] @ V^T
      bf16x8 pa[2];
      for (int c = 0; c < 2; ++c)
        pa[c] = *(const bf16x8*)(Ps + ll*128 + ((c*64 + lg*16) ^ ((ll & 7) << 4)));
      for (int dt = 0; dt < 8; ++dt) {
        int row = dt*16 + ll;
        for (int c = 0; c < 2; ++c) {
          bf16x8 vf = *(const bf16x8*)(Vs + row*128 + ((c*64 + lg*16) ^ ((row & 7) << 4)));
          acc[dt] = MFMA(pa[c], vf, acc[dt]);
        }
      }
      __syncthreads();
    }

    // normalize + write
    for (int dt = 0; dt < 8; ++dt) {
      int col = h*D + dt*16 + ll;
      for (int r = 0; r < 4; ++r) {
        int row = q0 + w*16 + lg*4 + r;
        float v = acc[dt][r] / sm[r];
        aout[(size_t)(b*T + row) * 2048 + col] = (bf16)v;
      }
    }
  }
}

// ---------------- launch ----------------

extern "C" void kernel_launch(void* const* d_in, const int* in_sizes, int n_in,
                              void* d_out, int out_size, void* d_ws, size_t ws_size,
                              hipStream_t stream) {
  const float* x  = (const float*)d_in[0];
  const float* fc = (const float*)d_in[1];
  const float* fs = (const float*)d_in[2];
  const float* wq = (const float*)d_in[4];
  const float* qb = (const float*)d_in[5];
  const float* wk = (const float*)d_in[6];
  const float* kb = (const float*)d_in[7];
  const float* wv = (const float*)d_in[8];
  const float* vb = (const float*)d_in[9];
  const float* wo = (const float*)d_in[10];
  const float* ob = (const float*)d_in[11];

  char* ws = (char*)d_ws;
  bf16*  x_bf   = (bf16*)(ws);                       // 16 MiB (reused as attn_out)
  bf16*  qkv    = (bf16*)(ws + 16777216);            // 18 MiB  (4096 x 2304)
  bf16*  wqkv_t = (bf16*)(ws + 35651584);            // 9 MiB   (2304 x 2048)
  bf16*  wo_t   = (bf16*)(ws + 45088768);            // 8 MiB   (2048 x 2048)
  bf16*  v_t    = (bf16*)(ws + 53477376);            // 1 MiB   (2 x 128 x 2048)
  float* qkvb   = (float*)(ws + 54525952);           // 9216 B
  bf16*  a_out  = x_bf;

  cvt_bf16<<<8192, 256, 0, stream>>>(x, x_bf, 2097152);
  transpose_w<<<dim3(64,64), dim3(32,8), 0, stream>>>(wq, wqkv_t, 2048);
  transpose_w<<<dim3(4,64),  dim3(32,8), 0, stream>>>(wk, wqkv_t + (size_t)2048*2048, 128);
  transpose_w<<<dim3(4,64),  dim3(32,8), 0, stream>>>(wv, wqkv_t + (size_t)2176*2048, 128);
  transpose_w<<<dim3(64,64), dim3(32,8), 0, stream>>>(wo, wo_t, 2048);
  concat_bias<<<9, 256, 0, stream>>>(qb, kb, vb, qkvb);

  gemm_bt256<false><<<dim3(9,16), 512, 0, stream>>>(x_bf, wqkv_t, qkv, qkvb, 4096, 2304, 2048);

  rope_q<<<16384, 256, 0, stream>>>(qkv, fc, fs);
  rope_k<<<1024, 256, 0, stream>>>(qkv, fc, fs);
  transpose_v<<<dim3(64,4,2), dim3(32,8), 0, stream>>>(qkv, v_t);

  attn_kernel<<<dim3(16,16,2), 256, 0, stream>>>(qkv, v_t, a_out);

  gemm_bt256<true><<<dim3(8,16), 512, 0, stream>>>(a_out, wo_t, d_out, ob, 4096, 2048, 2048);
}